// Round 15
// baseline (81.796 us; speedup 1.0000x reference)
//
#include <hip/hip_runtime.h>
#include <math.h>

#define KCOMP 32
#define DDIM 64
#define LOG_2PI 1.8378770664093453f

// W~ fragment-major layout: frag index f = (comp*2 + r)*5 + s, each frag is
// 1024 B = 64 lanes x 16 B (one half8 per lane). Per comp: 10 frags = 10240 B.
#define WFRAG_HALF8S 64
#define WCOMP_BYTES 10240

typedef _Float16 half8 __attribute__((ext_vector_type(8)));
typedef float floatx16 __attribute__((ext_vector_type(16)));

__device__ inline float rdlane(float v, int l) {
    return __uint_as_float(__builtin_amdgcn_readlane(__float_as_uint(v), l));
}

// ---------------------------------------------------------------------------
// Prep: ROLLED fused Cholesky + triangular inverse with VECTORIZED LDS
// operands. Lane t owns row t of L and (transposed) column t of M, both in
// LDS with 16B-chunk XOR swizzle: element (row, c) lives at
//   buf[row*64 + ((c>>2) ^ (row&15))*4 + (c&3)]
// -> per-lane ds_read_b128 of 4 consecutive elements is phase-conflict-free
// (within each 16-lane phase, (t&15) keys are all distinct).
// Per step j (runtime loop, ~4 KB total code, I$-resident):
//   chol dot:  dot_t = sum_{c<j} L[t][c] * L[j][c]
//   inv  dot:  ms_t  = sum_{c<j} L[j][c] * MT[t][c]     (MT[t][c] = M[c][t])
// 16 terms/iter = 12 independent b128 loads (broadcast Lj chunks uniform ->
// free) + 32 FMAs into 8 accumulators. Diagonal broadcast via v_readlane
// with runtime SGPR lane index. No barriers (1 wave); in-wave LDS ordering
// is lgkmcnt-automatic. grid = KCOMP blocks x 64 threads (1 wave/CU shape:
// best measured across the R11/R12/R14 wave-packing A/B series).
// ---------------------------------------------------------------------------
__global__ __launch_bounds__(64, 1) void gmm_prep(const float* __restrict__ loc,
                                                  const float* __restrict__ cov,
                                                  const float* __restrict__ pi,
                                                  _Float16* __restrict__ wt,
                                                  float* __restrict__ cstout)
{
    const int k = blockIdx.x;
    const int t = threadIdx.x;

    __shared__ float Lb[DDIM * DDIM];     // L, swizzled rows (16 KB)
    __shared__ float Mb[DDIM * DDIM];     // M^T, swizzled rows (16 KB)
    __shared__ float mu_s[DDIM];

    mu_s[t] = loc[k * DDIM + t];

    const float* sg = cov + (size_t)k * DDIM * DDIM + (size_t)t * DDIM; // Sigma row t
    const int key = t & 15;
    float* Lt = Lb + t * 64;              // lane-private row base (L row t)
    float* Mt = Mb + t * 64;              // lane-private row base (M col t)

    float mydiag = 1.f;                   // lane t ends holding d_t
    float scur = sg[0];

    #pragma unroll 1
    for (int j = 0; j < DDIM; ++j) {
        float snext = sg[(j + 1 < DDIM) ? (j + 1) : (DDIM - 1)];

        const float* Lj = Lb + j * 64;    // broadcast row (uniform address)
        const int jkey = j & 15;

        float a0 = 0.f, a1 = 0.f, a2 = 0.f, a3 = 0.f;
        float m0 = 0.f, m1 = 0.f, m2 = 0.f, m3 = 0.f;

        const int j4 = j >> 2;            // complete 4-float chunks
        int c4 = 0;
        #pragma unroll 1
        for (; c4 + 4 <= j4; c4 += 4) {   // 16 terms per iteration
            float4 b0 = *(const float4*)(Lj + ((c4 + 0) ^ jkey) * 4);
            float4 b1 = *(const float4*)(Lj + ((c4 + 1) ^ jkey) * 4);
            float4 b2 = *(const float4*)(Lj + ((c4 + 2) ^ jkey) * 4);
            float4 b3 = *(const float4*)(Lj + ((c4 + 3) ^ jkey) * 4);
            float4 l0 = *(const float4*)(Lt + ((c4 + 0) ^ key) * 4);
            float4 l1 = *(const float4*)(Lt + ((c4 + 1) ^ key) * 4);
            float4 l2 = *(const float4*)(Lt + ((c4 + 2) ^ key) * 4);
            float4 l3 = *(const float4*)(Lt + ((c4 + 3) ^ key) * 4);
            float4 q0 = *(const float4*)(Mt + ((c4 + 0) ^ key) * 4);
            float4 q1 = *(const float4*)(Mt + ((c4 + 1) ^ key) * 4);
            float4 q2 = *(const float4*)(Mt + ((c4 + 2) ^ key) * 4);
            float4 q3 = *(const float4*)(Mt + ((c4 + 3) ^ key) * 4);
            a0 += l0.x * b0.x + l0.y * b0.y + l0.z * b0.z + l0.w * b0.w;
            a1 += l1.x * b1.x + l1.y * b1.y + l1.z * b1.z + l1.w * b1.w;
            a2 += l2.x * b2.x + l2.y * b2.y + l2.z * b2.z + l2.w * b2.w;
            a3 += l3.x * b3.x + l3.y * b3.y + l3.z * b3.z + l3.w * b3.w;
            m0 += q0.x * b0.x + q0.y * b0.y + q0.z * b0.z + q0.w * b0.w;
            m1 += q1.x * b1.x + q1.y * b1.y + q1.z * b1.z + q1.w * b1.w;
            m2 += q2.x * b2.x + q2.y * b2.y + q2.z * b2.z + q2.w * b2.w;
            m3 += q3.x * b3.x + q3.y * b3.y + q3.z * b3.z + q3.w * b3.w;
        }
        #pragma unroll 1
        for (; c4 < j4; ++c4) {           // leftover whole chunks
            float4 b0 = *(const float4*)(Lj + (c4 ^ jkey) * 4);
            float4 l0 = *(const float4*)(Lt + (c4 ^ key) * 4);
            float4 q0 = *(const float4*)(Mt + (c4 ^ key) * 4);
            a0 += l0.x * b0.x + l0.y * b0.y + l0.z * b0.z + l0.w * b0.w;
            m0 += q0.x * b0.x + q0.y * b0.y + q0.z * b0.z + q0.w * b0.w;
        }
        #pragma unroll 1
        for (int c = j4 * 4; c < j; ++c) { // scalar remainder (<=3 terms)
            float bj = Lj[((c >> 2) ^ jkey) * 4 + (c & 3)];
            float lt = Lt[((c >> 2) ^ key) * 4 + (c & 3)];
            float qt = Mt[((c >> 2) ^ key) * 4 + (c & 3)];
            a0 += lt * bj;
            m0 += bj * qt;
        }

        float dot = (a0 + a1) + (a2 + a3);
        float ms  = (m0 + m1) + (m2 + m3);

        float v  = scur - dot;
        float dj = rdlane(v, j);              // runtime lane idx -> uniform
        float r  = rsqrtf(dj);
        r = r * (1.5f - 0.5f * dj * r * r);   // one Newton step
        const int woff = ((j >> 2) ^ key) * 4 + (j & 3);
        Lt[woff] = (t >= j) ? v * r : 0.f;                       // L[t][j]
        Mt[woff] = (t < j) ? (-ms * r) : ((t == j) ? r : 0.f);   // M[j][t]
        if (t == j) mydiag = dj;
        scur = snext;
    }

    // half-logdet = sum_j 0.5*log(d_j): one logf per lane + wave-sum
    float hld;
    {
        float lg = 0.5f * logf(mydiag);
        #pragma unroll
        for (int w = 1; w < 64; w <<= 1) lg += __shfl_xor(lg, w);
        hld = lg;
    }

    // ---- b_t = sum_q M[t][q] * mu[q] = sum_q MT(q, t) * mu[q] ----
    float bt = 0.f;
    #pragma unroll 1
    for (int q = 0; q < DDIM; ++q)
        bt += Mb[q * 64 + (((t >> 2) ^ (q & 15)) * 4) + (t & 3)] * mu_s[q];

    // ---- emit fragment-major f16 W~: thread t = z-row t ----
    // A-frag for mfma_32x32x16_f16: lane l holds A[l&31][(l>>5)*8 + e].
    // Row t, feature chunk c (8 halves) -> frag s = c>>1, frag-lane
    // fl = (t&31) + 32*(c&1), tile r = t>>5.  M[t][cc] = MT(cc, t).
    {
        const int r = t >> 5, lrow = t & 31;
        half8* wp = (half8*)wt;
        const size_t fbase = ((size_t)k * 2 + r) * 5;   // frag index base
        #pragma unroll 1
        for (int c = 0; c < 8; ++c) {          // data chunks: M row
            half8 v;
            #pragma unroll
            for (int e = 0; e < 8; ++e) {
                int cc = c * 8 + e;
                v[e] = (_Float16)Mb[cc * 64 + (((t >> 2) ^ (cc & 15)) * 4) + (t & 3)];
            }
            int fl = lrow + 32 * (c & 1);
            wp[(fbase + (c >> 1)) * WFRAG_HALF8S + fl] = v;
        }
        {   // chunk 8 (s=4, fl=lrow): -b split hi/lo (pairs with x~=1,1)
            float nb = -bt;
            _Float16 h0 = (_Float16)nb;
            _Float16 h1 = (_Float16)(nb - (float)h0);
            half8 v;
            #pragma unroll
            for (int e = 0; e < 8; ++e) v[e] = (_Float16)0.f;
            v[0] = h0; v[1] = h1;
            wp[(fbase + 4) * WFRAG_HALF8S + lrow] = v;
        }
        {   // chunk 9 (s=4, fl=lrow+32): zeros
            half8 v;
            #pragma unroll
            for (int e = 0; e < 8; ++e) v[e] = (_Float16)0.f;
            wp[(fbase + 4) * WFRAG_HALF8S + lrow + 32] = v;
        }
    }

    if (t == 0) {
        float mxp = pi[0];
        for (int i = 1; i < KCOMP; ++i) mxp = fmaxf(mxp, pi[i]);
        float s = 0.f;
        for (int i = 0; i < KCOMP; ++i) s += __expf(pi[i] - mxp);
        float lse = mxp + logf(s);
        cstout[k] = (pi[k] - lse) - hld - 0.5f * (float)DDIM * LOG_2PI;
    }
}

// ---------------------------------------------------------------------------
// Main: UNCHANGED from round 8. No LDS staging, no hot-loop barriers.
// Block = 4 waves = 4 component slices (8 comps each) over the SAME 128
// points; W~ fragments stream L2 -> regs double-buffered.
// ---------------------------------------------------------------------------
__global__ __launch_bounds__(256, 1) void gmm_main(const float* __restrict__ X,
                                                   const _Float16* __restrict__ wt,
                                                   const float* __restrict__ cst,
                                                   float* __restrict__ out)
{
    __shared__ float2 part[4][128];       // [slice][point] partial (mx, sm)

    const int tid  = threadIdx.x;
    const int wave = tid >> 6;            // = component slice
    const int lane = tid & 63;
    const int col  = lane & 31;
    const int h    = lane >> 5;
    const int ptbase = blockIdx.x * 128;

    // ---- build B fragments (x~) for 4 point-groups of 32 ----
    half8 bf[4][5];
    #pragma unroll
    for (int g = 0; g < 4; ++g) {
        const float* xr = X + (size_t)(ptbase + g * 32 + col) * DDIM;
        #pragma unroll
        for (int s = 0; s < 4; ++s) {
            int c = s * 2 + h;
            float4 lo = *(const float4*)(xr + c * 8);
            float4 hi = *(const float4*)(xr + c * 8 + 4);
            half8 v;
            v[0] = (_Float16)lo.x; v[1] = (_Float16)lo.y;
            v[2] = (_Float16)lo.z; v[3] = (_Float16)lo.w;
            v[4] = (_Float16)hi.x; v[5] = (_Float16)hi.y;
            v[6] = (_Float16)hi.z; v[7] = (_Float16)hi.w;
            bf[g][s] = v;
        }
        half8 v;
        #pragma unroll
        for (int e = 0; e < 8; ++e) v[e] = (_Float16)0.f;
        if (h == 0) { v[0] = (_Float16)1.f; v[1] = (_Float16)1.f; }
        bf[g][4] = v;   // augmented slice: pairs with (-b_hi, -b_lo)
    }

    const half8* wp = (const half8*)wt;
    const int comp0 = wave * 8;

    float mx[4], sm[4];
    #pragma unroll
    for (int g = 0; g < 4; ++g) { mx[g] = -INFINITY; sm[g] = 0.f; }

    half8 wfA[5], wfB[5];
    // preload tile-0 frags of first comp
    #pragma unroll
    for (int s = 0; s < 5; ++s)
        wfA[s] = wp[((size_t)comp0 * 2 + 0) * 5 * WFRAG_HALF8S + s * WFRAG_HALF8S + lane];

    #pragma unroll 1
    for (int q = 0; q < 8; ++q) {
        const int c = comp0 + q;

        // issue tile-1 frag loads (overlap with tile-0 MFMA below)
        #pragma unroll
        for (int s = 0; s < 5; ++s)
            wfB[s] = wp[((size_t)c * 2 + 1) * 5 * WFRAG_HALF8S + s * WFRAG_HALF8S + lane];

        float sP[4];

        {   // tile 0: z-rows 0..31
            floatx16 a0 = {0.f}, a1 = {0.f}, a2 = {0.f}, a3 = {0.f};
            #pragma unroll
            for (int s = 0; s < 5; ++s) {
                a0 = __builtin_amdgcn_mfma_f32_32x32x16_f16(wfA[s], bf[0][s], a0, 0, 0, 0);
                a1 = __builtin_amdgcn_mfma_f32_32x32x16_f16(wfA[s], bf[1][s], a1, 0, 0, 0);
                a2 = __builtin_amdgcn_mfma_f32_32x32x16_f16(wfA[s], bf[2][s], a2, 0, 0, 0);
                a3 = __builtin_amdgcn_mfma_f32_32x32x16_f16(wfA[s], bf[3][s], a3, 0, 0, 0);
            }
            float p0 = 0.f, p1 = 0.f, p2 = 0.f, p3 = 0.f;
            #pragma unroll
            for (int r = 0; r < 16; ++r) {
                p0 += a0[r] * a0[r]; p1 += a1[r] * a1[r];
                p2 += a2[r] * a2[r]; p3 += a3[r] * a3[r];
            }
            sP[0] = p0; sP[1] = p1; sP[2] = p2; sP[3] = p3;
        }

        // issue next comp's tile-0 loads (overlap with tile-1 MFMA below)
        if (q < 7) {
            #pragma unroll
            for (int s = 0; s < 5; ++s)
                wfA[s] = wp[((size_t)(c + 1) * 2 + 0) * 5 * WFRAG_HALF8S + s * WFRAG_HALF8S + lane];
        }

        {   // tile 1: z-rows 32..63
            floatx16 a0 = {0.f}, a1 = {0.f}, a2 = {0.f}, a3 = {0.f};
            #pragma unroll
            for (int s = 0; s < 5; ++s) {
                a0 = __builtin_amdgcn_mfma_f32_32x32x16_f16(wfB[s], bf[0][s], a0, 0, 0, 0);
                a1 = __builtin_amdgcn_mfma_f32_32x32x16_f16(wfB[s], bf[1][s], a1, 0, 0, 0);
                a2 = __builtin_amdgcn_mfma_f32_32x32x16_f16(wfB[s], bf[2][s], a2, 0, 0, 0);
                a3 = __builtin_amdgcn_mfma_f32_32x32x16_f16(wfB[s], bf[3][s], a3, 0, 0, 0);
            }
            float p0 = 0.f, p1 = 0.f, p2 = 0.f, p3 = 0.f;
            #pragma unroll
            for (int r = 0; r < 16; ++r) {
                p0 += a0[r] * a0[r]; p1 += a1[r] * a1[r];
                p2 += a2[r] * a2[r]; p3 += a3[r] * a3[r];
            }
            sP[0] += p0; sP[1] += p1; sP[2] += p2; sP[3] += p3;
        }

        const float ck = cst[c];
        #pragma unroll
        for (int g = 0; g < 4; ++g) {
            float sfull = sP[g] + __shfl_xor(sP[g], 32);
            float lp = ck - 0.5f * sfull;
            float nm = fmaxf(mx[g], lp);
            sm[g] = sm[g] * __expf(mx[g] - nm) + __expf(lp - nm);
            mx[g] = nm;
        }
    }

    // ---- merge the 4 slices in-block ----
    if (h == 0) {
        #pragma unroll
        for (int g = 0; g < 4; ++g)
            part[wave][g * 32 + col] = make_float2(mx[g], sm[g]);
    }
    __syncthreads();

    if (tid < 128) {
        float2 p0 = part[0][tid], p1 = part[1][tid];
        float2 p2 = part[2][tid], p3 = part[3][tid];
        float m = fmaxf(fmaxf(p0.x, p1.x), fmaxf(p2.x, p3.x));
        float s = p0.y * __expf(p0.x - m) + p1.y * __expf(p1.x - m)
                + p2.y * __expf(p2.x - m) + p3.y * __expf(p3.x - m);
        out[ptbase + tid] = m + logf(s);
    }
}

// ---------------------------------------------------------------------------
extern "C" void kernel_launch(void* const* d_in, const int* in_sizes, int n_in,
                              void* d_out, int out_size, void* d_ws, size_t ws_size,
                              hipStream_t stream) {
    const float* X   = (const float*)d_in[0];
    const float* loc = (const float*)d_in[1];
    const float* cov = (const float*)d_in[2];
    const float* pi  = (const float*)d_in[3];
    float* out = (float*)d_out;

    char* ws = (char*)d_ws;
    _Float16* wt = (_Float16*)ws;                              // 320 KB
    float* cstp  = (float*)(ws + (size_t)KCOMP * WCOMP_BYTES); // 128 B

    const int n = in_sizes[0] / DDIM;   // 65536

    gmm_prep<<<KCOMP, 64, 0, stream>>>(loc, cov, pi, wt, cstp);
    gmm_main<<<n / 128, 256, 0, stream>>>(X, wt, cstp, out);
}

// Round 16
// 45.831 us; speedup vs baseline: 1.7847x; 1.7847x over previous
//
#include <hip/hip_runtime.h>
#include <math.h>

#define KCOMP 32
#define DDIM 64
#define LOG_2PI 1.8378770664093453f

// W~ fragment-major layout: frag index f = (comp*2 + r)*5 + s, each frag is
// 1024 B = 64 lanes x 16 B (one half8 per lane). Per comp: 10 frags = 10240 B.
#define WFRAG_HALF8S 64
#define WCOMP_BYTES 10240

typedef _Float16 half8 __attribute__((ext_vector_type(8)));
typedef float floatx16 __attribute__((ext_vector_type(16)));
typedef float float2v __attribute__((ext_vector_type(2)));

__device__ inline float rdlane(float v, int l) {
    return __uint_as_float(__builtin_amdgcn_readlane(__float_as_uint(v), l));
}

// ---------------------------------------------------------------------------
// FUSED Cholesky + triangular-inverse step, fully static (template J),
// with PACKED fp32 pairs: LM[c] = (L[t][c], M[c][t]) lives in an even-
// aligned VGPR pair, so the fused dot is ONE v_pk_fma_f32 per term:
//   am[e].x += LM[c].x * b   (chol dot:  L[t][c] * L[J][c])
//   am[e].y += LM[c].y * b   (inv  dot:  M[c][t] * L[J][c])
// Halves the hot-loop FMA instruction count vs R11 (the measured prep cost
// tracks streamed instruction bytes). Math identical f32.
// Padding safety: LM zero-init; at step J, LM[c>=J] = 0.
// ---------------------------------------------------------------------------
template <int J>
__device__ __forceinline__ void fused_step(float (&Srow)[DDIM], float2v (&LM)[DDIM],
                                           float& mydiag, const int t) {
    constexpr int NPAD = ((J + 7) / 8) * 8;
    float2v am[8];
    #pragma unroll
    for (int e = 0; e < 8; ++e) am[e] = (float2v){0.f, 0.f};
    #pragma unroll
    for (int p8 = 0; p8 < NPAD; p8 += 8) {
        float b[8];
        #pragma unroll
        for (int e = 0; e < 8; ++e) b[e] = rdlane(LM[p8 + e].x, J);  // L[J][c]
        #pragma unroll
        for (int e = 0; e < 8; ++e) {
            float2v bb = {b[e], b[e]};
            am[e] += LM[p8 + e] * bb;        // v_pk_fma_f32
        }
    }
    float2v red = ((am[0] + am[1]) + (am[2] + am[3]))
                + ((am[4] + am[5]) + (am[6] + am[7]));
    float dot = red.x;
    float ms  = red.y;
    float v  = Srow[J] - dot;
    float dj = rdlane(v, J);                 // diagonal d_J (pre-sqrt), uniform
    float r  = rsqrtf(dj);
    r = r * (1.5f - 0.5f * dj * r * r);      // one Newton step
    float lv = (t >= J) ? v * r : 0.f;
    float mv = (t < J) ? (-ms * r) : ((t == J) ? r : 0.f);
    LM[J] = (float2v){lv, mv};
    if (t == J) mydiag = dj;
}

template <int J>
__device__ __forceinline__ void fused_run(float (&Srow)[DDIM], float2v (&LM)[DDIM],
                                          float& mydiag, const int t) {
    fused_step<J>(Srow, LM, mydiag, t);
    if constexpr (J + 1 < DDIM) fused_run<J + 1>(Srow, LM, mydiag, t);
}

// ---------------------------------------------------------------------------
// Prep: register-resident fused Cholesky+inverse, one wave/component.
// Launch shape reverted to the best-measured R11 config: 32 blocks x 64 thr
// (1 wave/CU; the R12/R14 packing A/B showed no gain / regression).
// ---------------------------------------------------------------------------
__global__ __launch_bounds__(64, 1) void gmm_prep(const float* __restrict__ loc,
                                                  const float* __restrict__ cov,
                                                  const float* __restrict__ pi,
                                                  _Float16* __restrict__ wt,
                                                  float* __restrict__ cstout)
{
    const int k = blockIdx.x;
    const int t = threadIdx.x;

    __shared__ float M[DDIM][DDIM + 1];
    __shared__ float mu_s[DDIM];

    float Srow[DDIM];     // Sigma row t
    float2v LM[DDIM];     // (L[t][c], M[c][t]) pairs (zero-init: padding safety)

    {
        const float4* Sg = (const float4*)(cov + (size_t)k * DDIM * DDIM + (size_t)t * DDIM);
        #pragma unroll
        for (int q = 0; q < DDIM / 4; ++q) {
            float4 v = Sg[q];
            Srow[q * 4 + 0] = v.x; Srow[q * 4 + 1] = v.y;
            Srow[q * 4 + 2] = v.z; Srow[q * 4 + 3] = v.w;
        }
    }
    #pragma unroll
    for (int i = 0; i < DDIM; ++i) LM[i] = (float2v){0.f, 0.f};
    mu_s[t] = loc[k * DDIM + t];

    // ---- fused left-looking Cholesky + forward-substitution inverse ----
    float mydiag = 1.f;                      // lane t ends holding d_t
    fused_run<0>(Srow, LM, mydiag, t);

    // half-logdet = sum_j 0.5*log(d_j): one logf per lane + wave-sum
    float hld;
    {
        float lg = 0.5f * logf(mydiag);
        #pragma unroll
        for (int w = 1; w < 64; w <<= 1) lg += __shfl_xor(lg, w);
        hld = lg;
    }

    // flush M columns -> LDS rows (one time)
    #pragma unroll
    for (int i = 0; i < DDIM; ++i) M[i][t] = LM[i].y;
    __syncthreads();

    // ---- b_t = sum_j M[t][j] * mu[j] (upper of M is zero) ----
    float bt = 0.f;
    #pragma unroll 4
    for (int j = 0; j < DDIM; ++j) bt += M[t][j] * mu_s[j];

    // ---- emit fragment-major f16 W~: thread t = z-row t ----
    // A-frag for mfma_32x32x16_f16: lane l holds A[l&31][(l>>5)*8 + e].
    // Row t, feature chunk c (8 halves) -> frag s = c>>1, frag-lane
    // fl = (t&31) + 32*(c&1), tile r = t>>5.
    {
        const int r = t >> 5, lrow = t & 31;
        half8* wp = (half8*)wt;
        const size_t fbase = ((size_t)k * 2 + r) * 5;   // frag index base
        #pragma unroll
        for (int c = 0; c < 8; ++c) {          // data chunks: M row
            half8 v;
            #pragma unroll
            for (int e = 0; e < 8; ++e) v[e] = (_Float16)M[t][c * 8 + e];
            int fl = lrow + 32 * (c & 1);
            wp[(fbase + (c >> 1)) * WFRAG_HALF8S + fl] = v;
        }
        {   // chunk 8 (s=4, fl=lrow): -b split hi/lo (pairs with x~=1,1)
            float nb = -bt;
            _Float16 h0 = (_Float16)nb;
            _Float16 h1 = (_Float16)(nb - (float)h0);
            half8 v;
            #pragma unroll
            for (int e = 0; e < 8; ++e) v[e] = (_Float16)0.f;
            v[0] = h0; v[1] = h1;
            wp[(fbase + 4) * WFRAG_HALF8S + lrow] = v;
        }
        {   // chunk 9 (s=4, fl=lrow+32): zeros
            half8 v;
            #pragma unroll
            for (int e = 0; e < 8; ++e) v[e] = (_Float16)0.f;
            wp[(fbase + 4) * WFRAG_HALF8S + lrow + 32] = v;
        }
    }

    if (t == 0) {
        float mxp = pi[0];
        for (int i = 1; i < KCOMP; ++i) mxp = fmaxf(mxp, pi[i]);
        float s = 0.f;
        for (int i = 0; i < KCOMP; ++i) s += __expf(pi[i] - mxp);
        float lse = mxp + logf(s);
        cstout[k] = (pi[k] - lse) - hld - 0.5f * (float)DDIM * LOG_2PI;
    }
}

// ---------------------------------------------------------------------------
// Main: UNCHANGED from round 8. No LDS staging, no hot-loop barriers.
// Block = 4 waves = 4 component slices (8 comps each) over the SAME 128
// points; W~ fragments stream L2 -> regs double-buffered.
// ---------------------------------------------------------------------------
__global__ __launch_bounds__(256, 1) void gmm_main(const float* __restrict__ X,
                                                   const _Float16* __restrict__ wt,
                                                   const float* __restrict__ cst,
                                                   float* __restrict__ out)
{
    __shared__ float2 part[4][128];       // [slice][point] partial (mx, sm)

    const int tid  = threadIdx.x;
    const int wave = tid >> 6;            // = component slice
    const int lane = tid & 63;
    const int col  = lane & 31;
    const int h    = lane >> 5;
    const int ptbase = blockIdx.x * 128;

    // ---- build B fragments (x~) for 4 point-groups of 32 ----
    half8 bf[4][5];
    #pragma unroll
    for (int g = 0; g < 4; ++g) {
        const float* xr = X + (size_t)(ptbase + g * 32 + col) * DDIM;
        #pragma unroll
        for (int s = 0; s < 4; ++s) {
            int c = s * 2 + h;
            float4 lo = *(const float4*)(xr + c * 8);
            float4 hi = *(const float4*)(xr + c * 8 + 4);
            half8 v;
            v[0] = (_Float16)lo.x; v[1] = (_Float16)lo.y;
            v[2] = (_Float16)lo.z; v[3] = (_Float16)lo.w;
            v[4] = (_Float16)hi.x; v[5] = (_Float16)hi.y;
            v[6] = (_Float16)hi.z; v[7] = (_Float16)hi.w;
            bf[g][s] = v;
        }
        half8 v;
        #pragma unroll
        for (int e = 0; e < 8; ++e) v[e] = (_Float16)0.f;
        if (h == 0) { v[0] = (_Float16)1.f; v[1] = (_Float16)1.f; }
        bf[g][4] = v;   // augmented slice: pairs with (-b_hi, -b_lo)
    }

    const half8* wp = (const half8*)wt;
    const int comp0 = wave * 8;

    float mx[4], sm[4];
    #pragma unroll
    for (int g = 0; g < 4; ++g) { mx[g] = -INFINITY; sm[g] = 0.f; }

    half8 wfA[5], wfB[5];
    // preload tile-0 frags of first comp
    #pragma unroll
    for (int s = 0; s < 5; ++s)
        wfA[s] = wp[((size_t)comp0 * 2 + 0) * 5 * WFRAG_HALF8S + s * WFRAG_HALF8S + lane];

    #pragma unroll 1
    for (int q = 0; q < 8; ++q) {
        const int c = comp0 + q;

        // issue tile-1 frag loads (overlap with tile-0 MFMA below)
        #pragma unroll
        for (int s = 0; s < 5; ++s)
            wfB[s] = wp[((size_t)c * 2 + 1) * 5 * WFRAG_HALF8S + s * WFRAG_HALF8S + lane];

        float sP[4];

        {   // tile 0: z-rows 0..31
            floatx16 a0 = {0.f}, a1 = {0.f}, a2 = {0.f}, a3 = {0.f};
            #pragma unroll
            for (int s = 0; s < 5; ++s) {
                a0 = __builtin_amdgcn_mfma_f32_32x32x16_f16(wfA[s], bf[0][s], a0, 0, 0, 0);
                a1 = __builtin_amdgcn_mfma_f32_32x32x16_f16(wfA[s], bf[1][s], a1, 0, 0, 0);
                a2 = __builtin_amdgcn_mfma_f32_32x32x16_f16(wfA[s], bf[2][s], a2, 0, 0, 0);
                a3 = __builtin_amdgcn_mfma_f32_32x32x16_f16(wfA[s], bf[3][s], a3, 0, 0, 0);
            }
            float p0 = 0.f, p1 = 0.f, p2 = 0.f, p3 = 0.f;
            #pragma unroll
            for (int r = 0; r < 16; ++r) {
                p0 += a0[r] * a0[r]; p1 += a1[r] * a1[r];
                p2 += a2[r] * a2[r]; p3 += a3[r] * a3[r];
            }
            sP[0] = p0; sP[1] = p1; sP[2] = p2; sP[3] = p3;
        }

        // issue next comp's tile-0 loads (overlap with tile-1 MFMA below)
        if (q < 7) {
            #pragma unroll
            for (int s = 0; s < 5; ++s)
                wfA[s] = wp[((size_t)(c + 1) * 2 + 0) * 5 * WFRAG_HALF8S + s * WFRAG_HALF8S + lane];
        }

        {   // tile 1: z-rows 32..63
            floatx16 a0 = {0.f}, a1 = {0.f}, a2 = {0.f}, a3 = {0.f};
            #pragma unroll
            for (int s = 0; s < 5; ++s) {
                a0 = __builtin_amdgcn_mfma_f32_32x32x16_f16(wfB[s], bf[0][s], a0, 0, 0, 0);
                a1 = __builtin_amdgcn_mfma_f32_32x32x16_f16(wfB[s], bf[1][s], a1, 0, 0, 0);
                a2 = __builtin_amdgcn_mfma_f32_32x32x16_f16(wfB[s], bf[2][s], a2, 0, 0, 0);
                a3 = __builtin_amdgcn_mfma_f32_32x32x16_f16(wfB[s], bf[3][s], a3, 0, 0, 0);
            }
            float p0 = 0.f, p1 = 0.f, p2 = 0.f, p3 = 0.f;
            #pragma unroll
            for (int r = 0; r < 16; ++r) {
                p0 += a0[r] * a0[r]; p1 += a1[r] * a1[r];
                p2 += a2[r] * a2[r]; p3 += a3[r] * a3[r];
            }
            sP[0] += p0; sP[1] += p1; sP[2] += p2; sP[3] += p3;
        }

        const float ck = cst[c];
        #pragma unroll
        for (int g = 0; g < 4; ++g) {
            float sfull = sP[g] + __shfl_xor(sP[g], 32);
            float lp = ck - 0.5f * sfull;
            float nm = fmaxf(mx[g], lp);
            sm[g] = sm[g] * __expf(mx[g] - nm) + __expf(lp - nm);
            mx[g] = nm;
        }
    }

    // ---- merge the 4 slices in-block ----
    if (h == 0) {
        #pragma unroll
        for (int g = 0; g < 4; ++g)
            part[wave][g * 32 + col] = make_float2(mx[g], sm[g]);
    }
    __syncthreads();

    if (tid < 128) {
        float2 p0 = part[0][tid], p1 = part[1][tid];
        float2 p2 = part[2][tid], p3 = part[3][tid];
        float m = fmaxf(fmaxf(p0.x, p1.x), fmaxf(p2.x, p3.x));
        float s = p0.y * __expf(p0.x - m) + p1.y * __expf(p1.x - m)
                + p2.y * __expf(p2.x - m) + p3.y * __expf(p3.x - m);
        out[ptbase + tid] = m + logf(s);
    }
}

// ---------------------------------------------------------------------------
extern "C" void kernel_launch(void* const* d_in, const int* in_sizes, int n_in,
                              void* d_out, int out_size, void* d_ws, size_t ws_size,
                              hipStream_t stream) {
    const float* X   = (const float*)d_in[0];
    const float* loc = (const float*)d_in[1];
    const float* cov = (const float*)d_in[2];
    const float* pi  = (const float*)d_in[3];
    float* out = (float*)d_out;

    char* ws = (char*)d_ws;
    _Float16* wt = (_Float16*)ws;                              // 320 KB
    float* cstp  = (float*)(ws + (size_t)KCOMP * WCOMP_BYTES); // 128 B

    const int n = in_sizes[0] / DDIM;   // 65536

    gmm_prep<<<KCOMP, 64, 0, stream>>>(loc, cov, pi, wt, cstp);
    gmm_main<<<n / 128, 256, 0, stream>>>(X, wt, cstp, out);
}